// Round 8
// baseline (312.976 us; speedup 1.0000x reference)
//
#include <hip/hip_runtime.h>
#include <math.h>

// Sizes fixed by the problem.
#define N_AG   512
#define HIDD   256
#define OBSD   128
// P = 512*511/2 = 130816 pairs, out = [P,3]

__device__ __forceinline__ void fma4(float4& acc, float4 a, float4 b){
    acc.x += a.x*b.x; acc.y += a.y*b.y; acc.z += a.z*b.z; acc.w += a.w*b.w;
}
__device__ __forceinline__ float hsum(float4 a){ return (a.x+a.y)+(a.z+a.w); }

// ---- shared GEMM-tile helpers: 64x64 output tile, K-chunks of 32, LDS [32][68] kk-major ----
__device__ __forceinline__ void stage_rows(float* dst, const float* __restrict__ src,
        int row0, int stride, int colbase, int t){
    #pragma unroll
    for (int half = 0; half < 2; ++half){
        int idx = half*256 + t;
        int row = idx >> 3, c4 = idx & 7;
        float4 v = *(const float4*)(src + (row0+row)*stride + colbase + c4*4);
        dst[(c4*4+0)*68 + row] = v.x;
        dst[(c4*4+1)*68 + row] = v.y;
        dst[(c4*4+2)*68 + row] = v.z;
        dst[(c4*4+3)*68 + row] = v.w;
    }
}
__device__ __forceinline__ void tile_compute(const float* As, const float* Bs,
        int tx, int ty, float4 acc[4]){
    #pragma unroll
    for (int kk = 0; kk < 32; ++kk){
        float4 a = *(const float4*)(As + kk*68 + ty*4);
        float4 b = *(const float4*)(Bs + kk*68 + tx*4);
        acc[0].x += a.x*b.x; acc[0].y += a.x*b.y; acc[0].z += a.x*b.z; acc[0].w += a.x*b.w;
        acc[1].x += a.y*b.x; acc[1].y += a.y*b.y; acc[1].z += a.y*b.z; acc[1].w += a.y*b.w;
        acc[2].x += a.z*b.x; acc[2].y += a.z*b.y; acc[2].z += a.z*b.z; acc[2].w += a.z*b.w;
        acc[3].x += a.w*b.x; acc[3].y += a.w*b.y; acc[3].z += a.w*b.z; acc[3].w += a.w*b.w;
    }
}

// ---------------- K1: hid = relu(inputs @ fc1_w.T + fc1_b) ----------------
__global__ __launch_bounds__(256, 2) void k_fc1(const float* __restrict__ in,
        const float* __restrict__ w, const float* __restrict__ b,
        float* __restrict__ hid){
    __shared__ float lin[8*OBSD];
    int at = blockIdx.y, ot = blockIdx.x, t = threadIdx.x;
    ((float4*)lin)[t] = ((const float4*)(in + at*8*OBSD))[t];
    __syncthreads();
    int ol = t & 63, g = t >> 6;
    int o = ot*64 + ol;
    const float4* w4 = (const float4*)(w + o*OBSD);
    const float4* la = (const float4*)(lin + (g*2)*OBSD);
    const float4* lb = (const float4*)(lin + (g*2+1)*OBSD);
    float4 a0 = {0,0,0,0}, a1 = {0,0,0,0};
    #pragma unroll
    for (int c = 0; c < OBSD/4; ++c){
        float4 wv = w4[c];
        fma4(a0, la[c], wv);
        fma4(a1, lb[c], wv);
    }
    float bb = b[o];
    int ag = at*8 + g*2;
    hid[ag*HIDD + o]     = fmaxf(hsum(a0) + bb, 0.f);
    hid[(ag+1)*HIDD + o] = fmaxf(hsum(a1) + bb, 0.f);
}

// ---------------- K2: qkv = hid @ in_proj_w.T + in_proj_b ----------------
__global__ __launch_bounds__(256, 2) void k_qkv(const float* __restrict__ hid,
        const float* __restrict__ w, const float* __restrict__ b,
        float* __restrict__ qkv){
    __shared__ float lin[8*HIDD];
    int at = blockIdx.y, ot = blockIdx.x, t = threadIdx.x;
    const float4* in4 = (const float4*)(hid + at*8*HIDD);
    ((float4*)lin)[t]       = in4[t];
    ((float4*)lin)[t + 256] = in4[t + 256];
    __syncthreads();
    int ol = t & 63, g = t >> 6;
    int o = ot*64 + ol;                       // 0..767
    const float4* w4 = (const float4*)(w + o*HIDD);
    const float4* la = (const float4*)(lin + (g*2)*HIDD);
    const float4* lb = (const float4*)(lin + (g*2+1)*HIDD);
    float4 a0 = {0,0,0,0}, a1 = {0,0,0,0};
    #pragma unroll 8
    for (int c = 0; c < HIDD/4; ++c){
        float4 wv = w4[c];
        fma4(a0, la[c], wv);
        fma4(a1, lb[c], wv);
    }
    float bb = b[o];
    int ag = at*8 + g*2;
    qkv[ag*768 + o]     = hsum(a0) + bb;
    qkv[(ag+1)*768 + o] = hsum(a1) + bb;
}

// ---------------- K3: blocks 0..511 PERSISTENT vfc2_w stream | 512..575 scores | 576..607 VW ----------------
// Stream: 32 row-groups (8 rows) x 16 K-slices (8192 floats). Each block runs an 8-step
// sequential loop (1 hid load + 8 weight loads per step, unroll 2) so the wave keeps
// ~18 loads continuously in flight -- no per-block burst/die churn (R1/R4/R6/R7 all ~65us
// regardless of in-block ILP; the invariant was 2048 tiny one-burst blocks).
__global__ __launch_bounds__(256) void k_big(const float* __restrict__ qkv,
        const float* __restrict__ ow, const float* __restrict__ hid,
        const float* __restrict__ vw_w, float* __restrict__ S,
        float* __restrict__ VW, float* __restrict__ partial){
    __shared__ float As[32*68];
    __shared__ float Bs[32*68];
    int t = threadIdx.x;
    int bid = blockIdx.x;
    if (bid < 512){
        int slice = bid & 15, g = bid >> 4;     // slice 0..15, row-group 0..31
        int cbase = slice*2048;                 // float4 units (8192 floats per slice)
        const float4* h4 = (const float4*)hid + cbase;
        const float4* w4 = (const float4*)vw_w;
        int rb[8];
        #pragma unroll
        for (int r = 0; r < 8; ++r) rb[r] = (g*8+r)*32768 + cbase;
        float4 acc[8] = {{0,0,0,0},{0,0,0,0},{0,0,0,0},{0,0,0,0},
                         {0,0,0,0},{0,0,0,0},{0,0,0,0},{0,0,0,0}};
        #pragma unroll 2
        for (int step = 0; step < 8; ++step){
            int o = step*256 + t;
            float4 hv = h4[o];
            #pragma unroll
            for (int r = 0; r < 8; ++r)
                fma4(acc[r], hv, w4[rb[r] + o]);
        }
        #pragma unroll
        for (int r = 0; r < 8; ++r)
            partial[(g*8+r)*4096 + slice*256 + t] = hsum(acc[r]);
        return;
    }
    if (bid < 576){
        // ---- scores tile: S[i0+..64][j0+..64] = dot(Q_i, K_j) * 0.0625 ----
        int b2 = bid - 512;
        int ti = b2 >> 3, tj = b2 & 7;
        int i0 = ti*64, j0 = tj*64;
        int tx = t & 15, ty = t >> 4;
        float4 acc[4] = {{0,0,0,0},{0,0,0,0},{0,0,0,0},{0,0,0,0}};
        for (int k0 = 0; k0 < 256; k0 += 32){
            __syncthreads();
            stage_rows(As, qkv, i0, 768, k0,       t);   // Q chunk
            stage_rows(Bs, qkv, j0, 768, 256 + k0, t);   // K chunk
            __syncthreads();
            tile_compute(As, Bs, tx, ty, acc);
        }
        #pragma unroll
        for (int r = 0; r < 4; ++r){
            float4 o;
            o.x = acc[r].x*0.0625f; o.y = acc[r].y*0.0625f;
            o.z = acc[r].z*0.0625f; o.w = acc[r].w*0.0625f;
            *(float4*)(S + (i0+ty*4+r)*512 + j0 + tx*4) = o;
        }
        return;
    }
    // ---- VW tile: VW[j0+..64][d0+..64] = dot(V_j, ow_d) ----
    int b2 = bid - 576;
    int ti = b2 >> 2, tj = b2 & 3;
    int j0 = ti*64, d0 = tj*64;
    int tx = t & 15, ty = t >> 4;
    float4 acc[4] = {{0,0,0,0},{0,0,0,0},{0,0,0,0},{0,0,0,0}};
    for (int k0 = 0; k0 < 256; k0 += 32){
        __syncthreads();
        stage_rows(As, qkv, j0, 768, 512 + k0, t);   // V chunk
        stage_rows(Bs, ow,  d0, 256, k0,       t);   // ow chunk
        __syncthreads();
        tile_compute(As, Bs, tx, ty, acc);
    }
    #pragma unroll
    for (int r = 0; r < 4; ++r)
        *(float4*)(VW + (j0+ty*4+r)*256 + d0 + tx*4) = acc[r];
}

// ---------------- K4: blocks 0..127 row-softmax on S | blocks 128..383 value-row reduce ----------------
__global__ __launch_bounds__(256, 2) void k_soft_vred(float* __restrict__ S,
        const float* __restrict__ partial, const float* __restrict__ vb,
        const float* __restrict__ v3w, float* __restrict__ vred){
    int t = threadIdx.x;
    if (blockIdx.x >= 128){
        // reduce 4096 per-thread partials of row o; vred[o] = relu(sum+vb)*v3w
        int o = blockIdx.x - 128;
        const float4* p4 = (const float4*)(partial + o*4096);
        float4 a = {0,0,0,0};
        #pragma unroll
        for (int k = 0; k < 4; ++k){
            float4 v = p4[k*256 + t];
            a.x += v.x; a.y += v.y; a.z += v.z; a.w += v.w;
        }
        float s = hsum(a);
        for (int off = 32; off; off >>= 1) s += __shfl_xor(s, off);
        __shared__ float red[4];
        int lane = t & 63, wid = t >> 6;
        if (lane == 0) red[wid] = s;
        __syncthreads();
        if (t == 0){
            float tot = red[0]+red[1]+red[2]+red[3];
            vred[o] = fmaxf(tot + vb[o], 0.f) * v3w[o];
        }
        return;
    }
    int w = t >> 6, ln = t & 63;
    float* row = S + (blockIdx.x*4 + w)*512;
    float v[8];
    float m = -1e30f;
    #pragma unroll
    for (int k = 0; k < 8; ++k){ v[k] = row[ln + k*64]; m = fmaxf(m, v[k]); }
    for (int off = 32; off; off >>= 1) m = fmaxf(m, __shfl_xor(m, off));
    float s = 0.f;
    #pragma unroll
    for (int k = 0; k < 8; ++k){ v[k] = expf(v[k] - m); s += v[k]; }
    for (int off = 32; off; off >>= 1) s += __shfl_xor(s, off);
    float inv = 1.f / s;
    #pragma unroll
    for (int k = 0; k < 8; ++k) row[ln + k*64] = v[k]*inv;
}

// ---------------- K5: h = P @ VW + ob, grid 32 (8 i-tiles x 4 d-tiles) ----------------
__global__ __launch_bounds__(256, 2) void k_h(const float* __restrict__ P,
        const float* __restrict__ VW, const float* __restrict__ ob,
        float* __restrict__ hout){
    __shared__ float As[32*68];
    __shared__ float Bs[32*68];
    int bid = blockIdx.x;
    int ti = bid >> 2, tj = bid & 3;
    int i0 = ti*64, d0 = tj*64;
    int t = threadIdx.x, tx = t & 15, ty = t >> 4;
    float4 acc[4] = {{0,0,0,0},{0,0,0,0},{0,0,0,0},{0,0,0,0}};
    for (int k0 = 0; k0 < 512; k0 += 32){
        __syncthreads();
        stage_rows(As, P, i0, 512, k0, t);               // P chunk (transposed)
        #pragma unroll
        for (int half = 0; half < 2; ++half){
            int idx = half*256 + t;
            int kkr = idx >> 4, c4 = idx & 15;
            *(float4*)(Bs + kkr*68 + c4*4) = *(const float4*)(VW + (k0+kkr)*256 + d0 + c4*4);
        }
        __syncthreads();
        tile_compute(As, Bs, tx, ty, acc);
    }
    float4 bb = *(const float4*)(ob + d0 + tx*4);
    #pragma unroll
    for (int r = 0; r < 4; ++r){
        float4 o;
        o.x = acc[r].x + bb.x; o.y = acc[r].y + bb.y;
        o.z = acc[r].z + bb.z; o.w = acc[r].w + bb.w;
        *(float4*)(hout + (i0+ty*4+r)*256 + d0 + tx*4) = o;
    }
}

// ---------------- K6: A/B projections (blocks 0..511) || value finish (block 512) ----------------
__global__ __launch_bounds__(256, 2) void k_ab_value(const float* __restrict__ hin,
        const float* __restrict__ w2, const float* __restrict__ b2,
        const float* __restrict__ vred, const float* __restrict__ v3b,
        float* __restrict__ A, float* __restrict__ B, float* __restrict__ value){
    int t = threadIdx.x;
    if (blockIdx.x == 512){
        float s = vred[t];
        for (int off = 32; off; off >>= 1) s += __shfl_xor(s, off);
        __shared__ float redv[4];
        int lane = t & 63, wid = t >> 6;
        if (lane == 0) redv[wid] = s;
        __syncthreads();
        if (t == 0) value[0] = redv[0]+redv[1]+redv[2]+redv[3] + v3b[0];
        return;
    }
    __shared__ float lin[8*HIDD];
    int id = blockIdx.x, at = id >> 3, ot = id & 7;
    const float4* in4 = (const float4*)(hin + at*8*HIDD);
    ((float4*)lin)[t]       = in4[t];
    ((float4*)lin)[t + 256] = in4[t + 256];
    __syncthreads();
    int ol = t & 63, g = t >> 6;
    int o2 = ot*64 + ol;                   // 0..511
    bool isA = o2 < HIDD;
    int o = isA ? o2 : o2 - HIDD;
    const float4* w4 = (const float4*)(w2 + o*512 + (isA ? 0 : HIDD));
    const float4* la = (const float4*)(lin + (g*2)*HIDD);
    const float4* lb = (const float4*)(lin + (g*2+1)*HIDD);
    float4 acc0 = {0,0,0,0}, acc1 = {0,0,0,0};
    #pragma unroll 8
    for (int c = 0; c < HIDD/4; ++c){
        float4 wv = w4[c];
        fma4(acc0, la[c], wv);
        fma4(acc1, lb[c], wv);
    }
    int a0 = at*8 + g*2;
    float* dst = isA ? A : B;
    float bb = isA ? b2[o] : 0.f;          // fold fc2_b into A
    dst[a0*HIDD + o]     = hsum(acc0) + bb;
    dst[(a0+1)*HIDD + o] = hsum(acc1) + bb;
}

// ---------------- K7: per-pair x=relu(A[i]+B[j]); out = [sigmoid(wd.x+bd), 1-., value] ----------------
__global__ __launch_bounds__(256, 2) void k_pairs(const float* __restrict__ A,
        const float* __restrict__ B, const float* __restrict__ w3,
        const float* __restrict__ b3, const float* __restrict__ value,
        float* __restrict__ out){
    int ti = blockIdx.x, tj = blockIdx.y;
    if (tj < ti) return;                   // strictly-lower tiles have no pairs
    __shared__ float la[16*260], lb[16*260], lw[256];
    int t = threadIdx.x;
    #pragma unroll
    for (int l = 0; l < 4; ++l){
        int idx = l*256 + t;
        int r = idx >> 6, c4 = idx & 63;
        ((float4*)la)[r*65 + c4] = ((const float4*)A)[(ti*16 + r)*64 + c4];
        ((float4*)lb)[r*65 + c4] = ((const float4*)B)[(tj*16 + r)*64 + c4];
    }
    lw[t] = w3[t] - w3[256 + t];           // fc3_w[0]-fc3_w[1]
    __syncthreads();
    float val = value[0];
    float bd  = b3[0] - b3[1];
    int il = t >> 4, jl = t & 15;
    int i = ti*16 + il, j = tj*16 + jl;
    if (j > i){
        const float4* a4 = (const float4*)(la + il*260);
        const float4* b4 = (const float4*)(lb + jl*260);
        const float4* w4 = (const float4*)lw;
        float4 acc = {0,0,0,0};
        #pragma unroll 8
        for (int c = 0; c < 64; ++c){
            float4 aa = a4[c], bb = b4[c], wv = w4[c];
            acc.x += fmaxf(aa.x + bb.x, 0.f)*wv.x;
            acc.y += fmaxf(aa.y + bb.y, 0.f)*wv.y;
            acc.z += fmaxf(aa.z + bb.z, 0.f)*wv.z;
            acc.w += fmaxf(aa.w + bb.w, 0.f)*wv.w;
        }
        float z = hsum(acc) + bd;
        float o0 = 1.f/(1.f + expf(-z));
        int p = i*511 - (i*(i-1))/2 + (j - i - 1);
        out[3*p]   = o0;
        out[3*p+1] = 1.f - o0;
        out[3*p+2] = val;
    }
}

extern "C" void kernel_launch(void* const* d_in, const int* in_sizes, int n_in,
                              void* d_out, int out_size, void* d_ws, size_t ws_size,
                              hipStream_t stream){
    const float* inputs = (const float*)d_in[0];
    const float* fc1_w  = (const float*)d_in[1];
    const float* fc1_b  = (const float*)d_in[2];
    const float* inp_w  = (const float*)d_in[3];
    const float* inp_b  = (const float*)d_in[4];
    const float* outp_w = (const float*)d_in[5];
    const float* outp_b = (const float*)d_in[6];
    const float* fc2_w  = (const float*)d_in[7];
    const float* fc2_b  = (const float*)d_in[8];
    const float* fc3_w  = (const float*)d_in[9];
    const float* fc3_b  = (const float*)d_in[10];
    const float* vfc2_w = (const float*)d_in[11];
    const float* vfc2_b = (const float*)d_in[12];
    const float* vfc3_w = (const float*)d_in[13];
    const float* vfc3_b = (const float*)d_in[14];
    float* out = (float*)d_out;
    float* ws  = (float*)d_ws;
    // ws layout (floats)
    float* hid     = ws;              // 512*256   = 131072
    float* qkv     = ws + 131072;     // 512*768   = 393216
    float* S       = ws + 524288;     // 512*512   = 262144  (scores -> softmax in place)
    float* VW      = ws + 786432;     // 512*256   = 131072
    float* h       = ws + 917504;     // 512*256   = 131072
    float* A       = ws + 1048576;    // 512*256   = 131072
    float* B       = ws + 1179648;    // 512*256   = 131072
    float* partial = ws + 1310720;    // 256*4096  = 1048576 (4 MB per-thread partials)
    float* vred    = ws + 2359296;    // 256
    float* value   = ws + 2359552;    // 1

    k_fc1      <<<dim3(4, 64),  256, 0, stream>>>(inputs, fc1_w, fc1_b, hid);
    k_qkv      <<<dim3(12, 64), 256, 0, stream>>>(hid, inp_w, inp_b, qkv);
    k_big      <<<dim3(608),    256, 0, stream>>>(qkv, outp_w, hid, vfc2_w, S, VW, partial);
    k_soft_vred<<<dim3(384),    256, 0, stream>>>(S, partial, vfc2_b, vfc3_w, vred);
    k_h        <<<dim3(32),     256, 0, stream>>>(S, VW, outp_b, h);
    k_ab_value <<<dim3(513),    256, 0, stream>>>(h, fc2_w, fc2_b, vred, vfc3_b, A, B, value);
    k_pairs    <<<dim3(32, 32), 256, 0, stream>>>(A, B, fc3_w, fc3_b, value, out);
}

// Round 9
// 309.648 us; speedup vs baseline: 1.0107x; 1.0107x over previous
//
#include <hip/hip_runtime.h>
#include <math.h>

// Sizes fixed by the problem.
#define N_AG   512
#define HIDD   256
#define OBSD   128
// P = 512*511/2 = 130816 pairs, out = [P,3]

typedef float v4f __attribute__((ext_vector_type(4)));

#if __has_builtin(__builtin_nontemporal_load)
#define NTLOAD(p) __builtin_nontemporal_load(p)
#else
#define NTLOAD(p) (*(p))
#endif

__device__ __forceinline__ void fma4(float4& acc, float4 a, float4 b){
    acc.x += a.x*b.x; acc.y += a.y*b.y; acc.z += a.z*b.z; acc.w += a.w*b.w;
}
__device__ __forceinline__ float hsum(float4 a){ return (a.x+a.y)+(a.z+a.w); }
__device__ __forceinline__ float hsumv(v4f a){ return (a.x+a.y)+(a.z+a.w); }

// ---- value-head stream unit: 2 rows x 1 K-slice (8192 floats). q in [0,2048). ----
// Weights are single-use -> non-temporal loads (don't thrash L2 for co-resident chain blocks).
// Block-sum + one atomicAdd per row into rowacc (zeroed in k_fc1).
__device__ __forceinline__ void stream_unit(int q, int t, const float* __restrict__ hid,
        const float* __restrict__ vw, float* __restrict__ rowacc, float* red8){
    int rg = q >> 4, s = q & 15;
    const v4f* h4 = (const v4f*)hid + s*2048;
    const v4f* w0 = (const v4f*)vw + (long)(rg*2)*32768 + s*2048;
    const v4f* w1 = w0 + 32768;
    v4f a0 = {0,0,0,0}, a1 = {0,0,0,0};
    #pragma unroll
    for (int k = 0; k < 8; ++k){
        int o = k*256 + t;
        v4f hv = h4[o];
        a0 += hv * NTLOAD(w0 + o);
        a1 += hv * NTLOAD(w1 + o);
    }
    float s0 = hsumv(a0), s1 = hsumv(a1);
    for (int off = 32; off; off >>= 1){
        s0 += __shfl_xor(s0, off);
        s1 += __shfl_xor(s1, off);
    }
    int lane = t & 63, wid = t >> 6;
    if (lane == 0){ red8[wid] = s0; red8[4+wid] = s1; }
    __syncthreads();
    if (t == 0) atomicAdd(rowacc + rg*2,     red8[0]+red8[1]+red8[2]+red8[3]);
    if (t == 64) atomicAdd(rowacc + rg*2 + 1, red8[4]+red8[5]+red8[6]+red8[7]);
}

// ---- shared GEMM-tile helpers: 64x64 output tile, K-chunks of 32, LDS [32][68] kk-major ----
__device__ __forceinline__ void stage_rows(float* dst, const float* __restrict__ src,
        int row0, int stride, int colbase, int t){
    #pragma unroll
    for (int half = 0; half < 2; ++half){
        int idx = half*256 + t;
        int row = idx >> 3, c4 = idx & 7;
        float4 v = *(const float4*)(src + (row0+row)*stride + colbase + c4*4);
        dst[(c4*4+0)*68 + row] = v.x;
        dst[(c4*4+1)*68 + row] = v.y;
        dst[(c4*4+2)*68 + row] = v.z;
        dst[(c4*4+3)*68 + row] = v.w;
    }
}
__device__ __forceinline__ void tile_compute(const float* As, const float* Bs,
        int tx, int ty, float4 acc[4]){
    #pragma unroll
    for (int kk = 0; kk < 32; ++kk){
        float4 a = *(const float4*)(As + kk*68 + ty*4);
        float4 b = *(const float4*)(Bs + kk*68 + tx*4);
        acc[0].x += a.x*b.x; acc[0].y += a.x*b.y; acc[0].z += a.x*b.z; acc[0].w += a.x*b.w;
        acc[1].x += a.y*b.x; acc[1].y += a.y*b.y; acc[1].z += a.y*b.z; acc[1].w += a.y*b.w;
        acc[2].x += a.z*b.x; acc[2].y += a.z*b.y; acc[2].z += a.z*b.z; acc[2].w += a.z*b.w;
        acc[3].x += a.w*b.x; acc[3].y += a.w*b.y; acc[3].z += a.w*b.z; acc[3].w += a.w*b.w;
    }
}

// ---------------- K1: hid = relu(inputs @ fc1_w.T + fc1_b); block(0,0) zeroes rowacc ----------------
__global__ __launch_bounds__(256) void k_fc1(const float* __restrict__ in,
        const float* __restrict__ w, const float* __restrict__ b,
        float* __restrict__ hid, float* __restrict__ rowacc){
    __shared__ float lin[8*OBSD];
    int at = blockIdx.y, ot = blockIdx.x, t = threadIdx.x;
    if (ot == 0 && at == 0) rowacc[t] = 0.f;   // stream accumulators start at 0 (ws is poisoned)
    ((float4*)lin)[t] = ((const float4*)(in + at*8*OBSD))[t];
    __syncthreads();
    int ol = t & 63, g = t >> 6;
    int o = ot*64 + ol;
    const float4* w4 = (const float4*)(w + o*OBSD);
    const float4* la = (const float4*)(lin + (g*2)*OBSD);
    const float4* lb = (const float4*)(lin + (g*2+1)*OBSD);
    float4 a0 = {0,0,0,0}, a1 = {0,0,0,0};
    #pragma unroll
    for (int c = 0; c < OBSD/4; ++c){
        float4 wv = w4[c];
        fma4(a0, la[c], wv);
        fma4(a1, lb[c], wv);
    }
    float bb = b[o];
    int ag = at*8 + g*2;
    hid[ag*HIDD + o]     = fmaxf(hsum(a0) + bb, 0.f);
    hid[(ag+1)*HIDD + o] = fmaxf(hsum(a1) + bb, 0.f);
}

// ---------------- K2: qkv (chain bids 0..767) || stream q=0..255 (bids 768..1023) ----------------
__global__ __launch_bounds__(256) void k_qkv(const float* __restrict__ hid,
        const float* __restrict__ w, const float* __restrict__ b,
        const float* __restrict__ vw, float* __restrict__ rowacc,
        float* __restrict__ qkv){
    __shared__ float lin[8*HIDD];
    int t = threadIdx.x, bid = blockIdx.x;
    if (bid >= 768){ stream_unit(bid - 768, t, hid, vw, rowacc, lin); return; }
    int ot = bid % 12, at = bid / 12;
    const float4* in4 = (const float4*)(hid + at*8*HIDD);
    ((float4*)lin)[t]       = in4[t];
    ((float4*)lin)[t + 256] = in4[t + 256];
    __syncthreads();
    int ol = t & 63, g = t >> 6;
    int o = ot*64 + ol;                       // 0..767
    const float4* w4 = (const float4*)(w + o*HIDD);
    const float4* la = (const float4*)(lin + (g*2)*HIDD);
    const float4* lb = (const float4*)(lin + (g*2+1)*HIDD);
    float4 a0 = {0,0,0,0}, a1 = {0,0,0,0};
    #pragma unroll 8
    for (int c = 0; c < HIDD/4; ++c){
        float4 wv = w4[c];
        fma4(a0, la[c], wv);
        fma4(a1, lb[c], wv);
    }
    float bb = b[o];
    int ag = at*8 + g*2;
    qkv[ag*768 + o]     = hsum(a0) + bb;
    qkv[(ag+1)*768 + o] = hsum(a1) + bb;
}

// ---------------- K3: stream q=256..1279 (bids 0..1023) | scores (1024..1087) | VW (1088..1119) ----------------
__global__ __launch_bounds__(256) void k_big(const float* __restrict__ qkv,
        const float* __restrict__ ow, const float* __restrict__ hid,
        const float* __restrict__ vw, float* __restrict__ rowacc,
        float* __restrict__ S, float* __restrict__ VW){
    __shared__ float As[32*68];
    __shared__ float Bs[32*68];
    int t = threadIdx.x, bid = blockIdx.x;
    if (bid < 1024){ stream_unit(256 + bid, t, hid, vw, rowacc, As); return; }
    if (bid < 1088){
        // ---- scores tile: S[i0+..64][j0+..64] = dot(Q_i, K_j) * 0.0625 ----
        int b2 = bid - 1024;
        int ti = b2 >> 3, tj = b2 & 7;
        int i0 = ti*64, j0 = tj*64;
        int tx = t & 15, ty = t >> 4;
        float4 acc[4] = {{0,0,0,0},{0,0,0,0},{0,0,0,0},{0,0,0,0}};
        for (int k0 = 0; k0 < 256; k0 += 32){
            __syncthreads();
            stage_rows(As, qkv, i0, 768, k0,       t);   // Q chunk
            stage_rows(Bs, qkv, j0, 768, 256 + k0, t);   // K chunk
            __syncthreads();
            tile_compute(As, Bs, tx, ty, acc);
        }
        #pragma unroll
        for (int r = 0; r < 4; ++r){
            float4 o;
            o.x = acc[r].x*0.0625f; o.y = acc[r].y*0.0625f;
            o.z = acc[r].z*0.0625f; o.w = acc[r].w*0.0625f;
            *(float4*)(S + (i0+ty*4+r)*512 + j0 + tx*4) = o;
        }
        return;
    }
    // ---- VW tile: VW[j0+..64][d0+..64] = dot(V_j, ow_d) ----
    int b2 = bid - 1088;
    int ti = b2 >> 2, tj = b2 & 3;
    int j0 = ti*64, d0 = tj*64;
    int tx = t & 15, ty = t >> 4;
    float4 acc[4] = {{0,0,0,0},{0,0,0,0},{0,0,0,0},{0,0,0,0}};
    for (int k0 = 0; k0 < 256; k0 += 32){
        __syncthreads();
        stage_rows(As, qkv, j0, 768, 512 + k0, t);   // V chunk
        stage_rows(Bs, ow,  d0, 256, k0,       t);   // ow chunk
        __syncthreads();
        tile_compute(As, Bs, tx, ty, acc);
    }
    #pragma unroll
    for (int r = 0; r < 4; ++r)
        *(float4*)(VW + (j0+ty*4+r)*256 + d0 + tx*4) = acc[r];
}

// ---------------- K4: stream q=1280..1535 (bids 0..255) | row-softmax on S (bids 256..383) ----------------
__global__ __launch_bounds__(256) void k_soft(float* __restrict__ S,
        const float* __restrict__ hid, const float* __restrict__ vw,
        float* __restrict__ rowacc){
    int t = threadIdx.x, bid = blockIdx.x;
    if (bid < 256){
        __shared__ float red8[8];
        stream_unit(1280 + bid, t, hid, vw, rowacc, red8);
        return;
    }
    int w = t >> 6, ln = t & 63;
    float* row = S + ((bid-256)*4 + w)*512;
    float v[8];
    float m = -1e30f;
    #pragma unroll
    for (int k = 0; k < 8; ++k){ v[k] = row[ln + k*64]; m = fmaxf(m, v[k]); }
    for (int off = 32; off; off >>= 1) m = fmaxf(m, __shfl_xor(m, off));
    float s = 0.f;
    #pragma unroll
    for (int k = 0; k < 8; ++k){ v[k] = expf(v[k] - m); s += v[k]; }
    for (int off = 32; off; off >>= 1) s += __shfl_xor(s, off);
    float inv = 1.f / s;
    #pragma unroll
    for (int k = 0; k < 8; ++k) row[ln + k*64] = v[k]*inv;
}

// ---------------- K5: stream q=1536..1791 (bids 0..255) | h = P @ VW + ob (bids 256..287) ----------------
__global__ __launch_bounds__(256) void k_h(const float* __restrict__ P,
        const float* __restrict__ VW, const float* __restrict__ ob,
        const float* __restrict__ hid, const float* __restrict__ vw,
        float* __restrict__ rowacc, float* __restrict__ hout){
    __shared__ float As[32*68];
    __shared__ float Bs[32*68];
    int t = threadIdx.x, bid = blockIdx.x;
    if (bid < 256){ stream_unit(1536 + bid, t, hid, vw, rowacc, As); return; }
    int b2 = bid - 256;
    int ti = b2 >> 2, tj = b2 & 3;
    int i0 = ti*64, d0 = tj*64;
    int tx = t & 15, ty = t >> 4;
    float4 acc[4] = {{0,0,0,0},{0,0,0,0},{0,0,0,0},{0,0,0,0}};
    for (int k0 = 0; k0 < 512; k0 += 32){
        __syncthreads();
        stage_rows(As, P, i0, 512, k0, t);               // P chunk (transposed)
        #pragma unroll
        for (int half = 0; half < 2; ++half){
            int idx = half*256 + t;
            int kkr = idx >> 4, c4 = idx & 15;
            *(float4*)(Bs + kkr*68 + c4*4) = *(const float4*)(VW + (k0+kkr)*256 + d0 + c4*4);
        }
        __syncthreads();
        tile_compute(As, Bs, tx, ty, acc);
    }
    float4 bb = *(const float4*)(ob + d0 + tx*4);
    #pragma unroll
    for (int r = 0; r < 4; ++r){
        float4 o;
        o.x = acc[r].x + bb.x; o.y = acc[r].y + bb.y;
        o.z = acc[r].z + bb.z; o.w = acc[r].w + bb.w;
        *(float4*)(hout + (i0+ty*4+r)*256 + d0 + tx*4) = o;
    }
}

// ---------------- K6: stream q=1792..2047 (bids 0..255) | A/B projections (bids 256..767) ----------------
__global__ __launch_bounds__(256) void k_ab(const float* __restrict__ hin,
        const float* __restrict__ w2, const float* __restrict__ b2,
        const float* __restrict__ hid, const float* __restrict__ vw,
        float* __restrict__ rowacc, float* __restrict__ A, float* __restrict__ B){
    __shared__ float lin[8*HIDD];
    int t = threadIdx.x, bid = blockIdx.x;
    if (bid < 256){ stream_unit(1792 + bid, t, hid, vw, rowacc, lin); return; }
    int id = bid - 256, at = id >> 3, ot = id & 7;
    const float4* in4 = (const float4*)(hin + at*8*HIDD);
    ((float4*)lin)[t]       = in4[t];
    ((float4*)lin)[t + 256] = in4[t + 256];
    __syncthreads();
    int ol = t & 63, g = t >> 6;
    int o2 = ot*64 + ol;                   // 0..511
    bool isA = o2 < HIDD;
    int o = isA ? o2 : o2 - HIDD;
    const float4* w4 = (const float4*)(w2 + o*512 + (isA ? 0 : HIDD));
    const float4* la = (const float4*)(lin + (g*2)*HIDD);
    const float4* lb = (const float4*)(lin + (g*2+1)*HIDD);
    float4 acc0 = {0,0,0,0}, acc1 = {0,0,0,0};
    #pragma unroll 8
    for (int c = 0; c < HIDD/4; ++c){
        float4 wv = w4[c];
        fma4(acc0, la[c], wv);
        fma4(acc1, lb[c], wv);
    }
    int a0 = at*8 + g*2;
    float* dst = isA ? A : B;
    float bb = isA ? b2[o] : 0.f;          // fold fc2_b into A
    dst[a0*HIDD + o]     = hsum(acc0) + bb;
    dst[(a0+1)*HIDD + o] = hsum(acc1) + bb;
}

// ---------------- K7: per-pair; each block finalizes value from rowacc (1KB, L2-hot) ----------------
__global__ __launch_bounds__(256) void k_pairs(const float* __restrict__ A,
        const float* __restrict__ B, const float* __restrict__ w3,
        const float* __restrict__ b3, const float* __restrict__ rowacc,
        const float* __restrict__ vb, const float* __restrict__ v3w,
        const float* __restrict__ v3b, float* __restrict__ out){
    int ti = blockIdx.x, tj = blockIdx.y;
    if (tj < ti) return;                   // strictly-lower tiles have no pairs
    __shared__ float la[16*260], lb[16*260], lw[256], red4[4];
    int t = threadIdx.x;
    // value = sum_r relu(rowacc[r]+vb[r])*v3w[r] + v3b
    float pv = fmaxf(rowacc[t] + vb[t], 0.f) * v3w[t];
    for (int off = 32; off; off >>= 1) pv += __shfl_xor(pv, off);
    int lane = t & 63, wid = t >> 6;
    if (lane == 0) red4[wid] = pv;
    #pragma unroll
    for (int l = 0; l < 4; ++l){
        int idx = l*256 + t;
        int r = idx >> 6, c4 = idx & 63;
        ((float4*)la)[r*65 + c4] = ((const float4*)A)[(ti*16 + r)*64 + c4];
        ((float4*)lb)[r*65 + c4] = ((const float4*)B)[(tj*16 + r)*64 + c4];
    }
    lw[t] = w3[t] - w3[256 + t];           // fc3_w[0]-fc3_w[1]
    __syncthreads();
    float val = red4[0]+red4[1]+red4[2]+red4[3] + v3b[0];
    float bd  = b3[0] - b3[1];
    int il = t >> 4, jl = t & 15;
    int i = ti*16 + il, j = tj*16 + jl;
    if (j > i){
        const float4* a4 = (const float4*)(la + il*260);
        const float4* b4 = (const float4*)(lb + jl*260);
        const float4* w4 = (const float4*)lw;
        float4 acc = {0,0,0,0};
        #pragma unroll 8
        for (int c = 0; c < 64; ++c){
            float4 aa = a4[c], bb = b4[c], wv = w4[c];
            acc.x += fmaxf(aa.x + bb.x, 0.f)*wv.x;
            acc.y += fmaxf(aa.y + bb.y, 0.f)*wv.y;
            acc.z += fmaxf(aa.z + bb.z, 0.f)*wv.z;
            acc.w += fmaxf(aa.w + bb.w, 0.f)*wv.w;
        }
        float z = hsum(acc) + bd;
        float o0 = 1.f/(1.f + expf(-z));
        int p = i*511 - (i*(i-1))/2 + (j - i - 1);
        out[3*p]   = o0;
        out[3*p+1] = 1.f - o0;
        out[3*p+2] = val;
    }
}

extern "C" void kernel_launch(void* const* d_in, const int* in_sizes, int n_in,
                              void* d_out, int out_size, void* d_ws, size_t ws_size,
                              hipStream_t stream){
    const float* inputs = (const float*)d_in[0];
    const float* fc1_w  = (const float*)d_in[1];
    const float* fc1_b  = (const float*)d_in[2];
    const float* inp_w  = (const float*)d_in[3];
    const float* inp_b  = (const float*)d_in[4];
    const float* outp_w = (const float*)d_in[5];
    const float* outp_b = (const float*)d_in[6];
    const float* fc2_w  = (const float*)d_in[7];
    const float* fc2_b  = (const float*)d_in[8];
    const float* fc3_w  = (const float*)d_in[9];
    const float* fc3_b  = (const float*)d_in[10];
    const float* vfc2_w = (const float*)d_in[11];
    const float* vfc2_b = (const float*)d_in[12];
    const float* vfc3_w = (const float*)d_in[13];
    const float* vfc3_b = (const float*)d_in[14];
    float* out = (float*)d_out;
    float* ws  = (float*)d_ws;
    // ws layout (floats)
    float* hid     = ws;              // 512*256   = 131072
    float* qkv     = ws + 131072;     // 512*768   = 393216
    float* S       = ws + 524288;     // 512*512   = 262144  (scores -> softmax in place)
    float* VW      = ws + 786432;     // 512*256   = 131072
    float* h       = ws + 917504;     // 512*256   = 131072
    float* A       = ws + 1048576;    // 512*256   = 131072
    float* B       = ws + 1179648;    // 512*256   = 131072
    float* rowacc  = ws + 1310720;    // 256 (value-head row accumulators, atomically updated)

    k_fc1  <<<dim3(4, 64),  256, 0, stream>>>(inputs, fc1_w, fc1_b, hid, rowacc);
    k_qkv  <<<dim3(1024),   256, 0, stream>>>(hid, inp_w, inp_b, vfc2_w, rowacc, qkv);
    k_big  <<<dim3(1120),   256, 0, stream>>>(qkv, outp_w, hid, vfc2_w, rowacc, S, VW);
    k_soft <<<dim3(384),    256, 0, stream>>>(S, hid, vfc2_w, rowacc);
    k_h    <<<dim3(288),    256, 0, stream>>>(S, VW, outp_b, hid, vfc2_w, rowacc, h);
    k_ab   <<<dim3(768),    256, 0, stream>>>(h, fc2_w, fc2_b, hid, vfc2_w, rowacc, A, B);
    k_pairs<<<dim3(32, 32), 256, 0, stream>>>(A, B, fc3_w, fc3_b, rowacc, vfc2_b, vfc3_w, vfc3_b, out);
}